// Round 10
// baseline (298.835 us; speedup 1.0000x reference)
//
#include <hip/hip_runtime.h>
#include <math.h>

#define N_USER 100000
#define N_ITEM 150000
#define NTOT   250000
#define D64    64
#define NNZ    1250000
#define BATCH  16384
#define GD     16
#define DSTATE 8
#define DCONV  4
#define DINNER 32
#define LSEQ   3
#define NBLK1  ((NTOT + 1023) >> 10)   // 245 scan blocks

// ---------------- mark node_ids rows (plain byte stores, no atomics) -------
__global__ void mark_nids_kernel(const int* __restrict__ nids,
                                 unsigned char* __restrict__ nidf,
                                 unsigned char* __restrict__ needf) {
    int b = blockIdx.x * 256 + threadIdx.x;
    if (b < BATCH) { int r = nids[b]; nidf[r] = 1; needf[r] = 1; }
}

// ---------------- mark cols needed as layer-2 sources (4 edges/thread) -----
__global__ void mark_need_kernel(const int* __restrict__ erow,
                                 const int* __restrict__ ecol,
                                 const unsigned char* __restrict__ nidf,
                                 unsigned char* __restrict__ needf) {
    int e = (blockIdx.x * 256 + threadIdx.x) * 4;
    if (e + 4 <= NNZ) {
        int4 r = *(const int4*)(erow + e);
        int4 c = *(const int4*)(ecol + e);
        if (nidf[r.x]) needf[c.x] = 1;
        if (nidf[r.y]) needf[c.y] = 1;
        if (nidf[r.z]) needf[c.z] = 1;
        if (nidf[r.w]) needf[c.w] = 1;
    } else {
        for (; e < NNZ; ++e) if (nidf[erow[e]]) needf[ecol[e]] = 1;
    }
}

// ---------------- histogram only (4 edges/thread) --------------------------
__global__ void hist_kernel(const int* __restrict__ erow,
                            const unsigned char* __restrict__ needf,
                            int* __restrict__ cnt) {
    int e = (blockIdx.x * 256 + threadIdx.x) * 4;
    if (e + 4 <= NNZ) {
        int4 r = *(const int4*)(erow + e);
        if (needf[r.x]) atomicAdd(&cnt[r.x], 1);
        if (needf[r.y]) atomicAdd(&cnt[r.y], 1);
        if (needf[r.z]) atomicAdd(&cnt[r.z], 1);
        if (needf[r.w]) atomicAdd(&cnt[r.w], 1);
    } else {
        for (; e < NNZ; ++e) {
            int r = erow[e];
            if (needf[r]) atomicAdd(&cnt[r], 1);
        }
    }
}

// ---------------- fused dual scan (decoupled lookback, ONE kernel) ---------
// Replaces scan1+scan2+scan3. 245 blocks, all co-resident (<=2048 capacity)
// so predecessor spin-wait cannot deadlock. partials[j] packs
// flag[63:62] | cntSum[61:32] | fposSum[31:0]; 0 = not published.
__device__ __forceinline__ unsigned long long pack_part(unsigned long long flag,
                                                        unsigned long long c,
                                                        unsigned long long f) {
    return (flag << 62) | (c << 32) | f;
}

__global__ __launch_bounds__(256) void scan_fused_kernel(
        const int* __restrict__ cnt, const unsigned char* __restrict__ flags,
        int* __restrict__ offs, int* __restrict__ cursor,
        int4* __restrict__ rowinfo, int* __restrict__ nrows,
        unsigned long long* __restrict__ partials) {
    __shared__ int lds[256];
    __shared__ int lfs[256];
    __shared__ int s_base[2];
    int t = threadIdx.x, blk = blockIdx.x;
    int base = (blk << 10) + (t << 2);
    int d0 = (base + 0 < NTOT) ? cnt[base + 0] : 0;
    int d1 = (base + 1 < NTOT) ? cnt[base + 1] : 0;
    int d2 = (base + 2 < NTOT) ? cnt[base + 2] : 0;
    int d3 = (base + 3 < NTOT) ? cnt[base + 3] : 0;
    int f0 = (base + 0 < NTOT) ? (int)flags[base + 0] : 0;
    int f1 = (base + 1 < NTOT) ? (int)flags[base + 1] : 0;
    int f2 = (base + 2 < NTOT) ? (int)flags[base + 2] : 0;
    int f3 = (base + 3 < NTOT) ? (int)flags[base + 3] : 0;
    int s  = d0 + d1 + d2 + d3;
    int fs = f0 + f1 + f2 + f3;
    lds[t] = s; lfs[t] = fs;
    __syncthreads();
    for (int off = 1; off < 256; off <<= 1) {
        int v  = (t >= off) ? lds[t - off] : 0;
        int fv = (t >= off) ? lfs[t - off] : 0;
        __syncthreads();
        lds[t] += v; lfs[t] += fv;
        __syncthreads();
    }
    int totC = lds[255], totF = lfs[255];

    if (t == 0) {
        if (blk == 0) {
            __hip_atomic_store(&partials[0], pack_part(2ull, (unsigned long long)totC,
                                                       (unsigned long long)totF),
                               __ATOMIC_RELEASE, __HIP_MEMORY_SCOPE_AGENT);
            s_base[0] = 0; s_base[1] = 0;
        } else {
            __hip_atomic_store(&partials[blk], pack_part(1ull, (unsigned long long)totC,
                                                         (unsigned long long)totF),
                               __ATOMIC_RELEASE, __HIP_MEMORY_SCOPE_AGENT);
            int accC = 0, accF = 0;
            for (int j = blk - 1; j >= 0; --j) {
                unsigned long long v;
                do {
                    v = __hip_atomic_load(&partials[j], __ATOMIC_ACQUIRE,
                                          __HIP_MEMORY_SCOPE_AGENT);
                } while ((v >> 62) == 0ull);
                accC += (int)((v >> 32) & 0x3FFFFFFFull);
                accF += (int)(v & 0xFFFFFFFFull);
                if ((v >> 62) == 2ull) break;
            }
            s_base[0] = accC; s_base[1] = accF;
            __hip_atomic_store(&partials[blk],
                               pack_part(2ull, (unsigned long long)(accC + totC),
                                         (unsigned long long)(accF + totF)),
                               __ATOMIC_RELEASE, __HIP_MEMORY_SCOPE_AGENT);
        }
    }
    __syncthreads();
    int baseC = s_base[0], baseF = s_base[1];

    int exclC = baseC + lds[t] - s;
    int exclF = baseF + lfs[t] - fs;
    int offv[4] = { exclC, exclC + d0, exclC + d0 + d1, exclC + d0 + d1 + d2 };
    int fpv[4]  = { exclF, exclF + f0, exclF + f0 + f1, exclF + f0 + f1 + f2 };
    int dv[4]   = { d0, d1, d2, d3 };
    int fv2[4]  = { f0, f1, f2, f3 };
    #pragma unroll
    for (int k = 0; k < 4; ++k) {
        int idx = base + k;
        if (idx < NTOT) {
            offs[idx] = offv[k];
            cursor[idx] = offv[k];
            if (fv2[k]) rowinfo[fpv[k]] = make_int4(idx, offv[k], offv[k] + dv[k], 0);
            if (idx == NTOT - 1) {
                offs[NTOT] = offv[k] + dv[k];
                nrows[0] = fpv[k] + fv2[k];
            }
        }
    }
}

// ---------------- CSR fill: cursor atomics (distributed, low contention) ---
__global__ void fill_kernel(const int* __restrict__ erow, const int* __restrict__ ecol,
                            const float* __restrict__ eval_,
                            int* __restrict__ cursor,
                            const unsigned char* __restrict__ needf,
                            int2* __restrict__ colval) {
    int e = (blockIdx.x * 256 + threadIdx.x) * 4;
    if (e + 4 <= NNZ) {
        int4   r = *(const int4*)(erow + e);
        int4   c = *(const int4*)(ecol + e);
        float4 v = *(const float4*)(eval_ + e);
        if (needf[r.x]) colval[atomicAdd(&cursor[r.x], 1)] = make_int2(c.x, __float_as_int(v.x));
        if (needf[r.y]) colval[atomicAdd(&cursor[r.y], 1)] = make_int2(c.y, __float_as_int(v.y));
        if (needf[r.z]) colval[atomicAdd(&cursor[r.z], 1)] = make_int2(c.z, __float_as_int(v.z));
        if (needf[r.w]) colval[atomicAdd(&cursor[r.w], 1)] = make_int2(c.w, __float_as_int(v.w));
    } else {
        for (; e < NNZ; ++e) {
            int r = erow[e];
            if (needf[r]) colval[atomicAdd(&cursor[r], 1)] = make_int2(ecol[e], __float_as_int(eval_[e]));
        }
    }
}

// ---------------- layer 1: quarter-wave per compacted row (int4 rowinfo) ---
__global__ __launch_bounds__(256) void layer1_kernel(const float* __restrict__ user,
                                                     const float* __restrict__ item,
                                                     const int*  __restrict__ nrows,
                                                     const int4* __restrict__ rowinfo,
                                                     const int2* __restrict__ colval,
                                                     float* __restrict__ dst) {
    const float4* user4 = (const float4*)user;
    const float4* item4 = (const float4*)item;

    int gid    = (blockIdx.x << 4) + (threadIdx.x >> 4);
    int lane16 = threadIdx.x & 15;
    if (gid >= nrows[0]) return;
    int4 ri = rowinfo[gid];               // {row, o0, o1, 0} — ONE load, no chain
    int row = ri.x, o0 = ri.y, o1 = ri.z;

    float4 acc = make_float4(0.f, 0.f, 0.f, 0.f);
    int i = o0;
    for (; i + 4 <= o1; i += 4) {
        int2 cv0 = colval[i], cv1 = colval[i + 1], cv2 = colval[i + 2], cv3 = colval[i + 3];
        const float4* s0 = (cv0.x < N_USER) ? user4 + (size_t)cv0.x * 16
                                            : item4 + (size_t)(cv0.x - N_USER) * 16;
        const float4* s1 = (cv1.x < N_USER) ? user4 + (size_t)cv1.x * 16
                                            : item4 + (size_t)(cv1.x - N_USER) * 16;
        const float4* s2 = (cv2.x < N_USER) ? user4 + (size_t)cv2.x * 16
                                            : item4 + (size_t)(cv2.x - N_USER) * 16;
        const float4* s3 = (cv3.x < N_USER) ? user4 + (size_t)cv3.x * 16
                                            : item4 + (size_t)(cv3.x - N_USER) * 16;
        float4 v0 = s0[lane16], v1 = s1[lane16], v2 = s2[lane16], v3 = s3[lane16];
        float w0 = __int_as_float(cv0.y), w1 = __int_as_float(cv1.y);
        float w2 = __int_as_float(cv2.y), w3 = __int_as_float(cv3.y);
        acc.x = fmaf(w3, v3.x, fmaf(w2, v2.x, fmaf(w1, v1.x, fmaf(w0, v0.x, acc.x))));
        acc.y = fmaf(w3, v3.y, fmaf(w2, v2.y, fmaf(w1, v1.y, fmaf(w0, v0.y, acc.y))));
        acc.z = fmaf(w3, v3.z, fmaf(w2, v2.z, fmaf(w1, v1.z, fmaf(w0, v0.z, acc.z))));
        acc.w = fmaf(w3, v3.w, fmaf(w2, v2.w, fmaf(w1, v1.w, fmaf(w0, v0.w, acc.w))));
    }
    for (; i < o1; ++i) {
        int2 cv = colval[i];
        const float4* s0 = (cv.x < N_USER) ? user4 + (size_t)cv.x * 16
                                           : item4 + (size_t)(cv.x - N_USER) * 16;
        float4 v = s0[lane16];
        float w = __int_as_float(cv.y);
        acc.x = fmaf(w, v.x, acc.x);
        acc.y = fmaf(w, v.y, acc.y);
        acc.z = fmaf(w, v.z, acc.z);
        acc.w = fmaf(w, v.w, acc.w);
    }

    float s = fmaf(acc.x, acc.x, fmaf(acc.y, acc.y, fmaf(acc.z, acc.z, acc.w * acc.w)));
    #pragma unroll
    for (int m = 8; m >= 1; m >>= 1) s += __shfl_xor(s, m, 64);
    float scale = 1.f / fmaxf(sqrtf(s), 1e-12f);
    float4 r;
    r.x = acc.x * scale; r.y = acc.y * scale; r.z = acc.z * scale; r.w = acc.w * scale;
    ((float4*)dst)[(size_t)row * 16 + lane16] = r;
}

// ---------------- fused head: 16 lanes per batch element -------------------
__global__ __launch_bounds__(256) void final_kernel(
    const int*   __restrict__ nids,
    const float* __restrict__ user,      const float* __restrict__ item,
    const float* __restrict__ embA,
    const int*   __restrict__ offs,      const int2* __restrict__ colval,
    const float* __restrict__ down_w,    const float* __restrict__ in_proj_w,
    const float* __restrict__ conv_w,    const float* __restrict__ conv_b,
    const float* __restrict__ x_proj_w,  const float* __restrict__ dt_proj_w,
    const float* __restrict__ dt_proj_b, const float* __restrict__ A_log,
    const float* __restrict__ D_param,   const float* __restrict__ out_proj_w,
    const float* __restrict__ ln_g,      const float* __restrict__ ln_b,
    const float* __restrict__ to_logit_w,const float* __restrict__ to_logit_b,
    float* __restrict__ out) {

    __shared__ float4 s_rows4[16 * 49];
    __shared__ float  s_downT[D64 * GD];
    __shared__ float  s_ipxT[GD * DINNER];
    __shared__ float  s_ipzT[GD * DINNER];
    __shared__ float  s_xpT[DINNER * 17];
    __shared__ float  s_opT[DINNER * GD];
    __shared__ float  s_AT[DSTATE * DINNER];
    __shared__ float4 s_cw4[DINNER];
    __shared__ float  s_cb[DINNER], s_dtw[DINNER], s_dtb[DINNER], s_Dp[DINNER];
    __shared__ float  s_lng[GD], s_lnb[GD], s_lw[GD];
    __shared__ float  s_lb;
    __shared__ float  s_g[16 * 49];
    __shared__ float  s_xs[16 * 98];
    __shared__ float  s_dbc[16 * 49];

    int t = threadIdx.x;
    int wave = t >> 6, lane = t & 63;
    int grp = lane >> 4, lane16 = lane & 15;
    int eb = wave * 4 + grp;
    int b  = blockIdx.x * 16 + eb;
    int nid = nids[b];

    // ---- stage rows 0,1 + inline layer-2 gather for row 2 ----
    {
        const float4* p0 = (const float4*)((nid < N_USER) ? user + (size_t)nid * D64
                                                          : item + (size_t)(nid - N_USER) * D64);
        const float4* p1 = (const float4*)(embA + (size_t)nid * D64);
        s_rows4[eb * 49 + 0 * 16 + lane16] = p0[lane16];
        s_rows4[eb * 49 + 1 * 16 + lane16] = p1[lane16];

        const float4* src4 = (const float4*)embA;
        int o0 = offs[nid], o1 = offs[nid + 1];
        float4 acc = make_float4(0.f, 0.f, 0.f, 0.f);
        int i = o0;
        for (; i + 4 <= o1; i += 4) {
            int2 cv0 = colval[i], cv1 = colval[i + 1], cv2 = colval[i + 2], cv3 = colval[i + 3];
            float4 v0 = src4[(size_t)cv0.x * 16 + lane16];
            float4 v1 = src4[(size_t)cv1.x * 16 + lane16];
            float4 v2 = src4[(size_t)cv2.x * 16 + lane16];
            float4 v3 = src4[(size_t)cv3.x * 16 + lane16];
            float w0 = __int_as_float(cv0.y), w1 = __int_as_float(cv1.y);
            float w2 = __int_as_float(cv2.y), w3 = __int_as_float(cv3.y);
            acc.x = fmaf(w3, v3.x, fmaf(w2, v2.x, fmaf(w1, v1.x, fmaf(w0, v0.x, acc.x))));
            acc.y = fmaf(w3, v3.y, fmaf(w2, v2.y, fmaf(w1, v1.y, fmaf(w0, v0.y, acc.y))));
            acc.z = fmaf(w3, v3.z, fmaf(w2, v2.z, fmaf(w1, v1.z, fmaf(w0, v0.z, acc.z))));
            acc.w = fmaf(w3, v3.w, fmaf(w2, v2.w, fmaf(w1, v1.w, fmaf(w0, v0.w, acc.w))));
        }
        for (; i < o1; ++i) {
            int2 cv = colval[i];
            float4 v = src4[(size_t)cv.x * 16 + lane16];
            float w = __int_as_float(cv.y);
            acc.x = fmaf(w, v.x, acc.x);
            acc.y = fmaf(w, v.y, acc.y);
            acc.z = fmaf(w, v.z, acc.z);
            acc.w = fmaf(w, v.w, acc.w);
        }
        float s = fmaf(acc.x, acc.x, fmaf(acc.y, acc.y, fmaf(acc.z, acc.z, acc.w * acc.w)));
        #pragma unroll
        for (int m = 8; m >= 1; m >>= 1) s += __shfl_xor(s, m, 64);
        float scale = 1.f / fmaxf(sqrtf(s), 1e-12f);
        float4 r;
        r.x = acc.x * scale; r.y = acc.y * scale; r.z = acc.z * scale; r.w = acc.w * scale;
        s_rows4[eb * 49 + 2 * 16 + lane16] = r;
    }

    // ---- stage + transpose weights ----
    for (int i = t; i < D64 * GD; i += 256) {
        int j = i & 15, d = i >> 4;
        s_downT[i] = down_w[j * D64 + d];
    }
    for (int i = t; i < GD * DINNER; i += 256) {
        int d = i & 31, j = i >> 5;
        s_ipxT[i] = in_proj_w[d * GD + j];
        s_ipzT[i] = in_proj_w[(d + DINNER) * GD + j];
    }
    for (int i = t; i < DINNER * 17; i += 256) {
        int d = i / 17, r = i % 17;
        s_xpT[i] = x_proj_w[r * DINNER + d];
    }
    for (int i = t; i < DINNER * GD; i += 256) {
        int j = i & 15, d = i >> 4;
        s_opT[i] = out_proj_w[j * DINNER + d];
    }
    for (int i = t; i < DSTATE * DINNER; i += 256) {
        int d = i & 31, s = i >> 5;
        s_AT[i] = -expf(A_log[d * DSTATE + s]);
    }
    if (t < DINNER) {
        s_cw4[t] = ((const float4*)conv_w)[t];
        s_cb[t] = conv_b[t]; s_dtw[t] = dt_proj_w[t];
        s_dtb[t] = dt_proj_b[t]; s_Dp[t] = D_param[t];
    }
    if (t < GD) { s_lng[t] = ln_g[t]; s_lnb[t] = ln_b[t]; s_lw[t] = to_logit_w[t]; }
    if (t == 0) s_lb = to_logit_b[0];
    __syncthreads();

    const float* rows = (const float*)s_rows4 + eb * 196;

    {
        float a0 = 0.f, a1 = 0.f, a2 = 0.f;
        #pragma unroll
        for (int d = 0; d < D64; ++d) {
            float w = s_downT[d * GD + lane16];
            a0 = fmaf(rows[d], w, a0);
            a1 = fmaf(rows[64 + d], w, a1);
            a2 = fmaf(rows[128 + d], w, a2);
        }
        s_g[eb * 49 + 0 * GD + lane16] = a0;
        s_g[eb * 49 + 1 * GD + lane16] = a1;
        s_g[eb * 49 + 2 * GD + lane16] = a2;
    }
    __syncthreads();

    const float* ge = s_g + eb * 49;

    float xsr[2][LSEQ];
    #pragma unroll
    for (int c = 0; c < 2; ++c) {
        int d = lane16 + 16 * c;
        float xl0 = 0.f, xl1 = 0.f, xl2 = 0.f;
        #pragma unroll
        for (int j = 0; j < GD; ++j) {
            float w = s_ipxT[j * DINNER + d];
            xl0 = fmaf(ge[j], w, xl0);
            xl1 = fmaf(ge[GD + j], w, xl1);
            xl2 = fmaf(ge[2 * GD + j], w, xl2);
        }
        float4 cw = s_cw4[d]; float cb = s_cb[d];
        float a0 = fmaf(xl0, cw.w, cb);
        float a1 = fmaf(xl1, cw.w, fmaf(xl0, cw.z, cb));
        float a2 = fmaf(xl2, cw.w, fmaf(xl1, cw.z, fmaf(xl0, cw.y, cb)));
        xsr[c][0] = a0 / (1.f + __expf(-a0));
        xsr[c][1] = a1 / (1.f + __expf(-a1));
        xsr[c][2] = a2 / (1.f + __expf(-a2));
        #pragma unroll
        for (int l = 0; l < LSEQ; ++l) s_xs[eb * 98 + l * DINNER + d] = xsr[c][l];
    }
    __syncthreads();

    {
        const float* xse = s_xs + eb * 98;
        int nr = (lane16 == 0) ? 2 : 1;
        for (int it = 0; it < nr; ++it) {
            int r = (it == 0) ? lane16 : 16;
            float a0 = 0.f, a1 = 0.f, a2 = 0.f;
            #pragma unroll
            for (int d = 0; d < DINNER; ++d) {
                float w = s_xpT[d * 17 + r];
                a0 = fmaf(xse[d], w, a0);
                a1 = fmaf(xse[DINNER + d], w, a1);
                a2 = fmaf(xse[2 * DINNER + d], w, a2);
            }
            s_dbc[eb * 49 + 0 * 17 + r] = a0;
            s_dbc[eb * 49 + 1 * 17 + r] = a1;
            s_dbc[eb * 49 + 2 * 17 + r] = a2;
        }
    }
    __syncthreads();

    {
        const float* dbce = s_dbc + eb * 49;
        float h[2][DSTATE];
        #pragma unroll
        for (int c = 0; c < 2; ++c)
            #pragma unroll
            for (int s = 0; s < DSTATE; ++s) h[c][s] = 0.f;
        #pragma unroll
        for (int l = 0; l < LSEQ; ++l) {
            float dtr = dbce[l * 17];
            float Bm[DSTATE], Cm[DSTATE];
            #pragma unroll
            for (int s = 0; s < DSTATE; ++s) {
                Bm[s] = dbce[l * 17 + 1 + s];
                Cm[s] = dbce[l * 17 + 9 + s];
            }
            #pragma unroll
            for (int c = 0; c < 2; ++c) {
                int d = lane16 + 16 * c;
                float pre = fmaf(dtr, s_dtw[d], s_dtb[d]);
                float dt  = (pre > 20.f) ? pre : __logf(1.f + __expf(pre));
                float xv  = xsr[c][l];
                float dtx = dt * xv;
                float acc = 0.f;
                #pragma unroll
                for (int s = 0; s < DSTATE; ++s) {
                    float dA = __expf(dt * s_AT[s * DINNER + d]);
                    h[c][s] = fmaf(dA, h[c][s], dtx * Bm[s]);
                    acc = fmaf(h[c][s], Cm[s], acc);
                }
                float y = fmaf(s_Dp[d], xv, acc);
                float zv = 0.f;
                #pragma unroll
                for (int j = 0; j < GD; ++j)
                    zv = fmaf(ge[l * GD + j], s_ipzT[j * DINNER + d], zv);
                float ys = y * (zv / (1.f + __expf(-zv)));
                s_xs[eb * 98 + l * DINNER + d] = ys;
            }
        }
    }
    __syncthreads();

    float lg[LSEQ];
    {
        const float* yse = s_xs + eb * 98;
        #pragma unroll
        for (int l = 0; l < LSEQ; ++l) {
            float a = 0.f;
            #pragma unroll
            for (int d = 0; d < DINNER; ++d)
                a = fmaf(yse[l * DINNER + d], s_opT[d * GD + lane16], a);
            float v = a + ge[l * GD + lane16];
            float sm = v, sq = v * v;
            #pragma unroll
            for (int m = 1; m <= 8; m <<= 1) {
                sm += __shfl_xor(sm, m, 64);
                sq += __shfl_xor(sq, m, 64);
            }
            float mu  = sm * (1.f / GD);
            float var = fmaxf(sq * (1.f / GD) - mu * mu, 0.f);
            float inv = rsqrtf(var + 1e-12f);
            float lo = fmaf(fmaf((v - mu) * inv, s_lng[lane16], s_lnb[lane16]),
                            s_lw[lane16], 0.f);
            #pragma unroll
            for (int m = 1; m <= 8; m <<= 1) lo += __shfl_xor(lo, m, 64);
            lg[l] = (lo + s_lb) * 1.25f;
        }
    }

    {
        float mx = fmaxf(lg[0], fmaxf(lg[1], lg[2]));
        float e0 = __expf(lg[0] - mx), e1 = __expf(lg[1] - mx), e2 = __expf(lg[2] - mx);
        float inv = 1.f / (e0 + e1 + e2);
        float w0 = e0 * inv, w1 = e1 * inv, w2 = e2 * inv;
        float4 r0 = s_rows4[eb * 49 + 0 * 16 + lane16];
        float4 r1 = s_rows4[eb * 49 + 1 * 16 + lane16];
        float4 r2 = s_rows4[eb * 49 + 2 * 16 + lane16];
        float4 r;
        r.x = w0 * r0.x + w1 * r1.x + w2 * r2.x;
        r.y = w0 * r0.y + w1 * r1.y + w2 * r2.y;
        r.z = w0 * r0.z + w1 * r1.z + w2 * r2.z;
        r.w = w0 * r0.w + w1 * r1.w + w2 * r2.w;
        ((float4*)out)[(size_t)b * 16 + lane16] = r;
    }
}

extern "C" void kernel_launch(void* const* d_in, const int* in_sizes, int n_in,
                              void* d_out, int out_size, void* d_ws, size_t ws_size,
                              hipStream_t stream) {
    const float* user      = (const float*)d_in[0];
    const float* item      = (const float*)d_in[1];
    const int*   erow      = (const int*)  d_in[2];
    const int*   ecol      = (const int*)  d_in[3];
    const float* eval_     = (const float*)d_in[4];
    const int*   nids      = (const int*)  d_in[5];
    const float* down_w    = (const float*)d_in[6];
    const float* in_proj_w = (const float*)d_in[7];
    const float* conv_w    = (const float*)d_in[8];
    const float* conv_b    = (const float*)d_in[9];
    const float* x_proj_w  = (const float*)d_in[10];
    const float* dt_proj_w = (const float*)d_in[11];
    const float* dt_proj_b = (const float*)d_in[12];
    const float* A_log     = (const float*)d_in[13];
    const float* D_param   = (const float*)d_in[14];
    const float* out_projw = (const float*)d_in[15];
    const float* ln_g      = (const float*)d_in[16];
    const float* ln_b      = (const float*)d_in[17];
    const float* to_lw     = (const float*)d_in[18];
    const float* to_lb     = (const float*)d_in[19];
    float* out = (float*)d_out;

    // workspace layout (~85 MB total)
    char* base = (char*)d_ws;
    float* embA = (float*)base;                                    // 64,000,000
    char* c = base + 64000000;
    // zeroed region (one memsetAsync): cnt | nidf | needf | partials
    int* cnt   = (int*)c;                                          // 1,000,000
    unsigned char* nidf  = (unsigned char*)(c + 1000000);          //   250,000
    unsigned char* needf = (unsigned char*)(c + 1250000);          //   250,000
    unsigned long long* partials = (unsigned long long*)(c + 1500000); // 2,048
    size_t zbytes = 1502048;
    c += 1502048;
    int* nrows    = (int*)c;  c += 64;
    int* cursor   = (int*)c;  c += (size_t)NTOT * 4;               // 1,000,000
    int* offs     = (int*)c;  c += (size_t)(NTOT + 1) * 4 + 60;    // 1,000,064
    int4* rowinfo = (int4*)c; c += (size_t)NTOT * 16;              // 4,000,000
    int2* colval  = (int2*)c;                                      // 10,000,000

    // ---- zero flags/counters/lookback-partials in one memset ----
    hipMemsetAsync((void*)cnt, 0, zbytes, stream);

    // ---- flag marking (plain byte stores, no atomics) ----
    mark_nids_kernel<<<(BATCH + 255) / 256, 256, 0, stream>>>(nids, nidf, needf);
    mark_need_kernel<<<(NNZ / 4 + 255) / 256, 256, 0, stream>>>(erow, ecol, nidf, needf);

    // ---- build (sparse) CSR: hist -> fused lookback scan -> fill ----
    hist_kernel<<<(NNZ / 4 + 255) / 256, 256, 0, stream>>>(erow, needf, cnt);
    scan_fused_kernel<<<NBLK1, 256, 0, stream>>>(cnt, needf, offs, cursor,
                                                 rowinfo, nrows, partials);
    fill_kernel<<<(NNZ / 4 + 255) / 256, 256, 0, stream>>>(erow, ecol, eval_, cursor,
                                                           needf, colval);

    // ---- layer 1 (compacted rows); layer 2 fused into final ----
    layer1_kernel<<<(NTOT + 15) / 16, 256, 0, stream>>>(user, item, nrows, rowinfo, colval, embA);

    // ---- fused head (incl. layer-2 gather): 16 elements per block ----
    final_kernel<<<BATCH / 16, 256, 0, stream>>>(nids, user, item, embA, offs, colval,
                                                 down_w, in_proj_w, conv_w, conv_b,
                                                 x_proj_w, dt_proj_w, dt_proj_b, A_log,
                                                 D_param, out_projw, ln_g, ln_b, to_lw, to_lb, out);
}

// Round 11
// 246.719 us; speedup vs baseline: 1.2112x; 1.2112x over previous
//
#include <hip/hip_runtime.h>
#include <math.h>

#define N_USER 100000
#define N_ITEM 150000
#define NTOT   250000
#define D64    64
#define NNZ    1250000
#define BATCH  16384
#define GD     16
#define DSTATE 8
#define DCONV  4
#define DINNER 32
#define LSEQ   3
#define NBLK1  ((NTOT + 1023) >> 10)   // 245 scan blocks

// ---------------- mark node_ids rows (plain byte stores, no atomics) -------
__global__ void mark_nids_kernel(const int* __restrict__ nids,
                                 unsigned char* __restrict__ nidf,
                                 unsigned char* __restrict__ needf) {
    int b = blockIdx.x * 256 + threadIdx.x;
    if (b < BATCH) { int r = nids[b]; nidf[r] = 1; needf[r] = 1; }
}

// ---------------- mark cols needed as layer-2 sources (4 edges/thread) -----
__global__ void mark_need_kernel(const int* __restrict__ erow,
                                 const int* __restrict__ ecol,
                                 const unsigned char* __restrict__ nidf,
                                 unsigned char* __restrict__ needf) {
    int e = (blockIdx.x * 256 + threadIdx.x) * 4;
    if (e + 4 <= NNZ) {
        int4 r = *(const int4*)(erow + e);
        int4 c = *(const int4*)(ecol + e);
        if (nidf[r.x]) needf[c.x] = 1;
        if (nidf[r.y]) needf[c.y] = 1;
        if (nidf[r.z]) needf[c.z] = 1;
        if (nidf[r.w]) needf[c.w] = 1;
    } else {
        for (; e < NNZ; ++e) if (nidf[erow[e]]) needf[ecol[e]] = 1;
    }
}

// ---------------- histogram only (4 edges/thread) --------------------------
__global__ void hist_kernel(const int* __restrict__ erow,
                            const unsigned char* __restrict__ needf,
                            int* __restrict__ cnt) {
    int e = (blockIdx.x * 256 + threadIdx.x) * 4;
    if (e + 4 <= NNZ) {
        int4 r = *(const int4*)(erow + e);
        if (needf[r.x]) atomicAdd(&cnt[r.x], 1);
        if (needf[r.y]) atomicAdd(&cnt[r.y], 1);
        if (needf[r.z]) atomicAdd(&cnt[r.z], 1);
        if (needf[r.w]) atomicAdd(&cnt[r.w], 1);
    } else {
        for (; e < NNZ; ++e) {
            int r = erow[e];
            if (needf[r]) atomicAdd(&cnt[r], 1);
        }
    }
}

// ---------------- dual exclusive scan: cnt -> offs, needf -> fpos ----------
// 3-kernel form (measured ~6 us total in R8 — the lookback fusion was a
// 62 us regression: 245-block serial poll chain at ~250 ns/hop).
__global__ __launch_bounds__(256) void scan1_kernel(const int* __restrict__ cnt,
                                                    const unsigned char* __restrict__ flags,
                                                    int* __restrict__ offs,
                                                    int* __restrict__ fpos,
                                                    int* __restrict__ bsum,
                                                    int* __restrict__ fbsum) {
    __shared__ int lds[256];
    __shared__ int lfs[256];
    int t = threadIdx.x;
    int base = (blockIdx.x << 10) + (t << 2);
    int d0 = (base + 0 < NTOT) ? cnt[base + 0] : 0;
    int d1 = (base + 1 < NTOT) ? cnt[base + 1] : 0;
    int d2 = (base + 2 < NTOT) ? cnt[base + 2] : 0;
    int d3 = (base + 3 < NTOT) ? cnt[base + 3] : 0;
    int f0 = (base + 0 < NTOT) ? (int)flags[base + 0] : 0;
    int f1 = (base + 1 < NTOT) ? (int)flags[base + 1] : 0;
    int f2 = (base + 2 < NTOT) ? (int)flags[base + 2] : 0;
    int f3 = (base + 3 < NTOT) ? (int)flags[base + 3] : 0;
    int s  = d0 + d1 + d2 + d3;
    int fs = f0 + f1 + f2 + f3;
    lds[t] = s; lfs[t] = fs;
    __syncthreads();
    for (int off = 1; off < 256; off <<= 1) {
        int v  = (t >= off) ? lds[t - off] : 0;
        int fv = (t >= off) ? lfs[t - off] : 0;
        __syncthreads();
        lds[t] += v; lfs[t] += fv;
        __syncthreads();
    }
    int excl  = lds[t] - s;
    int fexcl = lfs[t] - fs;
    if (base + 0 < NTOT) { offs[base + 0] = excl;                fpos[base + 0] = fexcl; }
    if (base + 1 < NTOT) { offs[base + 1] = excl + d0;           fpos[base + 1] = fexcl + f0; }
    if (base + 2 < NTOT) { offs[base + 2] = excl + d0 + d1;      fpos[base + 2] = fexcl + f0 + f1; }
    if (base + 3 < NTOT) { offs[base + 3] = excl + d0 + d1 + d2; fpos[base + 3] = fexcl + f0 + f1 + f2; }
    if (t == 255) { bsum[blockIdx.x] = lds[255]; fbsum[blockIdx.x] = lfs[255]; }
}

__global__ __launch_bounds__(256) void scan2_kernel(int* __restrict__ bsum,
                                                    int* __restrict__ fbsum) {
    __shared__ int lds[256];
    __shared__ int lfs[256];
    int t = threadIdx.x;
    int v0 = (t < NBLK1) ? bsum[t] : 0;
    int f0 = (t < NBLK1) ? fbsum[t] : 0;
    lds[t] = v0; lfs[t] = f0;
    __syncthreads();
    for (int off = 1; off < 256; off <<= 1) {
        int v  = (t >= off) ? lds[t - off] : 0;
        int fv = (t >= off) ? lfs[t - off] : 0;
        __syncthreads();
        lds[t] += v; lfs[t] += fv;
        __syncthreads();
    }
    if (t < NBLK1) { bsum[t] = lds[t] - v0; fbsum[t] = lfs[t] - f0; }
}

// scan3: finalize offs; init fill cursor; emit rowinfo {row,o0,o1}; nrows
__global__ void scan3_kernel(int* __restrict__ offs, const int* __restrict__ bsum,
                             const int* __restrict__ cnt,
                             const int* __restrict__ fpos, const int* __restrict__ fbsum,
                             const unsigned char* __restrict__ flags,
                             int* __restrict__ cursor,
                             int4* __restrict__ rowinfo, int* __restrict__ nrows) {
    int i = blockIdx.x * 256 + threadIdx.x;
    if (i >= NTOT) return;
    int v = offs[i] + bsum[i >> 10];
    int d = cnt[i];
    offs[i] = v;
    cursor[i] = v;
    int fp = fpos[i] + fbsum[i >> 10];
    int fl = flags[i];
    if (fl) rowinfo[fp] = make_int4(i, v, v + d, 0);
    if (i == NTOT - 1) {
        offs[NTOT] = v + d;
        nrows[0] = fp + fl;
    }
}

// ---------------- CSR fill: cursor atomics (distributed, low contention) ---
__global__ void fill_kernel(const int* __restrict__ erow, const int* __restrict__ ecol,
                            const float* __restrict__ eval_,
                            int* __restrict__ cursor,
                            const unsigned char* __restrict__ needf,
                            int2* __restrict__ colval) {
    int e = (blockIdx.x * 256 + threadIdx.x) * 4;
    if (e + 4 <= NNZ) {
        int4   r = *(const int4*)(erow + e);
        int4   c = *(const int4*)(ecol + e);
        float4 v = *(const float4*)(eval_ + e);
        if (needf[r.x]) colval[atomicAdd(&cursor[r.x], 1)] = make_int2(c.x, __float_as_int(v.x));
        if (needf[r.y]) colval[atomicAdd(&cursor[r.y], 1)] = make_int2(c.y, __float_as_int(v.y));
        if (needf[r.z]) colval[atomicAdd(&cursor[r.z], 1)] = make_int2(c.z, __float_as_int(v.z));
        if (needf[r.w]) colval[atomicAdd(&cursor[r.w], 1)] = make_int2(c.w, __float_as_int(v.w));
    } else {
        for (; e < NNZ; ++e) {
            int r = erow[e];
            if (needf[r]) colval[atomicAdd(&cursor[r], 1)] = make_int2(ecol[e], __float_as_int(eval_[e]));
        }
    }
}

// ---------------- layer 1: quarter-wave per compacted row (int4 rowinfo) ---
__global__ __launch_bounds__(256) void layer1_kernel(const float* __restrict__ user,
                                                     const float* __restrict__ item,
                                                     const int*  __restrict__ nrows,
                                                     const int4* __restrict__ rowinfo,
                                                     const int2* __restrict__ colval,
                                                     float* __restrict__ dst) {
    const float4* user4 = (const float4*)user;
    const float4* item4 = (const float4*)item;

    int gid    = (blockIdx.x << 4) + (threadIdx.x >> 4);
    int lane16 = threadIdx.x & 15;
    if (gid >= nrows[0]) return;
    int4 ri = rowinfo[gid];               // {row, o0, o1, 0} — ONE load, no chain
    int row = ri.x, o0 = ri.y, o1 = ri.z;

    float4 acc = make_float4(0.f, 0.f, 0.f, 0.f);
    int i = o0;
    for (; i + 4 <= o1; i += 4) {
        int2 cv0 = colval[i], cv1 = colval[i + 1], cv2 = colval[i + 2], cv3 = colval[i + 3];
        const float4* s0 = (cv0.x < N_USER) ? user4 + (size_t)cv0.x * 16
                                            : item4 + (size_t)(cv0.x - N_USER) * 16;
        const float4* s1 = (cv1.x < N_USER) ? user4 + (size_t)cv1.x * 16
                                            : item4 + (size_t)(cv1.x - N_USER) * 16;
        const float4* s2 = (cv2.x < N_USER) ? user4 + (size_t)cv2.x * 16
                                            : item4 + (size_t)(cv2.x - N_USER) * 16;
        const float4* s3 = (cv3.x < N_USER) ? user4 + (size_t)cv3.x * 16
                                            : item4 + (size_t)(cv3.x - N_USER) * 16;
        float4 v0 = s0[lane16], v1 = s1[lane16], v2 = s2[lane16], v3 = s3[lane16];
        float w0 = __int_as_float(cv0.y), w1 = __int_as_float(cv1.y);
        float w2 = __int_as_float(cv2.y), w3 = __int_as_float(cv3.y);
        acc.x = fmaf(w3, v3.x, fmaf(w2, v2.x, fmaf(w1, v1.x, fmaf(w0, v0.x, acc.x))));
        acc.y = fmaf(w3, v3.y, fmaf(w2, v2.y, fmaf(w1, v1.y, fmaf(w0, v0.y, acc.y))));
        acc.z = fmaf(w3, v3.z, fmaf(w2, v2.z, fmaf(w1, v1.z, fmaf(w0, v0.z, acc.z))));
        acc.w = fmaf(w3, v3.w, fmaf(w2, v2.w, fmaf(w1, v1.w, fmaf(w0, v0.w, acc.w))));
    }
    for (; i < o1; ++i) {
        int2 cv = colval[i];
        const float4* s0 = (cv.x < N_USER) ? user4 + (size_t)cv.x * 16
                                           : item4 + (size_t)(cv.x - N_USER) * 16;
        float4 v = s0[lane16];
        float w = __int_as_float(cv.y);
        acc.x = fmaf(w, v.x, acc.x);
        acc.y = fmaf(w, v.y, acc.y);
        acc.z = fmaf(w, v.z, acc.z);
        acc.w = fmaf(w, v.w, acc.w);
    }

    float s = fmaf(acc.x, acc.x, fmaf(acc.y, acc.y, fmaf(acc.z, acc.z, acc.w * acc.w)));
    #pragma unroll
    for (int m = 8; m >= 1; m >>= 1) s += __shfl_xor(s, m, 64);
    float scale = 1.f / fmaxf(sqrtf(s), 1e-12f);
    float4 r;
    r.x = acc.x * scale; r.y = acc.y * scale; r.z = acc.z * scale; r.w = acc.w * scale;
    ((float4*)dst)[(size_t)row * 16 + lane16] = r;
}

// ---------------- fused head: 16 lanes per batch element -------------------
__global__ __launch_bounds__(256) void final_kernel(
    const int*   __restrict__ nids,
    const float* __restrict__ user,      const float* __restrict__ item,
    const float* __restrict__ embA,
    const int*   __restrict__ offs,      const int2* __restrict__ colval,
    const float* __restrict__ down_w,    const float* __restrict__ in_proj_w,
    const float* __restrict__ conv_w,    const float* __restrict__ conv_b,
    const float* __restrict__ x_proj_w,  const float* __restrict__ dt_proj_w,
    const float* __restrict__ dt_proj_b, const float* __restrict__ A_log,
    const float* __restrict__ D_param,   const float* __restrict__ out_proj_w,
    const float* __restrict__ ln_g,      const float* __restrict__ ln_b,
    const float* __restrict__ to_logit_w,const float* __restrict__ to_logit_b,
    float* __restrict__ out) {

    __shared__ float4 s_rows4[16 * 49];
    __shared__ float  s_downT[D64 * GD];
    __shared__ float  s_ipxT[GD * DINNER];
    __shared__ float  s_ipzT[GD * DINNER];
    __shared__ float  s_xpT[DINNER * 17];
    __shared__ float  s_opT[DINNER * GD];
    __shared__ float  s_AT[DSTATE * DINNER];
    __shared__ float4 s_cw4[DINNER];
    __shared__ float  s_cb[DINNER], s_dtw[DINNER], s_dtb[DINNER], s_Dp[DINNER];
    __shared__ float  s_lng[GD], s_lnb[GD], s_lw[GD];
    __shared__ float  s_lb;
    __shared__ float  s_g[16 * 49];
    __shared__ float  s_xs[16 * 98];
    __shared__ float  s_dbc[16 * 49];

    int t = threadIdx.x;
    int wave = t >> 6, lane = t & 63;
    int grp = lane >> 4, lane16 = lane & 15;
    int eb = wave * 4 + grp;
    int b  = blockIdx.x * 16 + eb;
    int nid = nids[b];

    // ---- stage rows 0,1 + inline layer-2 gather for row 2 ----
    {
        const float4* p0 = (const float4*)((nid < N_USER) ? user + (size_t)nid * D64
                                                          : item + (size_t)(nid - N_USER) * D64);
        const float4* p1 = (const float4*)(embA + (size_t)nid * D64);
        s_rows4[eb * 49 + 0 * 16 + lane16] = p0[lane16];
        s_rows4[eb * 49 + 1 * 16 + lane16] = p1[lane16];

        const float4* src4 = (const float4*)embA;
        int o0 = offs[nid], o1 = offs[nid + 1];
        float4 acc = make_float4(0.f, 0.f, 0.f, 0.f);
        int i = o0;
        for (; i + 4 <= o1; i += 4) {
            int2 cv0 = colval[i], cv1 = colval[i + 1], cv2 = colval[i + 2], cv3 = colval[i + 3];
            float4 v0 = src4[(size_t)cv0.x * 16 + lane16];
            float4 v1 = src4[(size_t)cv1.x * 16 + lane16];
            float4 v2 = src4[(size_t)cv2.x * 16 + lane16];
            float4 v3 = src4[(size_t)cv3.x * 16 + lane16];
            float w0 = __int_as_float(cv0.y), w1 = __int_as_float(cv1.y);
            float w2 = __int_as_float(cv2.y), w3 = __int_as_float(cv3.y);
            acc.x = fmaf(w3, v3.x, fmaf(w2, v2.x, fmaf(w1, v1.x, fmaf(w0, v0.x, acc.x))));
            acc.y = fmaf(w3, v3.y, fmaf(w2, v2.y, fmaf(w1, v1.y, fmaf(w0, v0.y, acc.y))));
            acc.z = fmaf(w3, v3.z, fmaf(w2, v2.z, fmaf(w1, v1.z, fmaf(w0, v0.z, acc.z))));
            acc.w = fmaf(w3, v3.w, fmaf(w2, v2.w, fmaf(w1, v1.w, fmaf(w0, v0.w, acc.w))));
        }
        for (; i < o1; ++i) {
            int2 cv = colval[i];
            float4 v = src4[(size_t)cv.x * 16 + lane16];
            float w = __int_as_float(cv.y);
            acc.x = fmaf(w, v.x, acc.x);
            acc.y = fmaf(w, v.y, acc.y);
            acc.z = fmaf(w, v.z, acc.z);
            acc.w = fmaf(w, v.w, acc.w);
        }
        float s = fmaf(acc.x, acc.x, fmaf(acc.y, acc.y, fmaf(acc.z, acc.z, acc.w * acc.w)));
        #pragma unroll
        for (int m = 8; m >= 1; m >>= 1) s += __shfl_xor(s, m, 64);
        float scale = 1.f / fmaxf(sqrtf(s), 1e-12f);
        float4 r;
        r.x = acc.x * scale; r.y = acc.y * scale; r.z = acc.z * scale; r.w = acc.w * scale;
        s_rows4[eb * 49 + 2 * 16 + lane16] = r;
    }

    // ---- stage + transpose weights ----
    for (int i = t; i < D64 * GD; i += 256) {
        int j = i & 15, d = i >> 4;
        s_downT[i] = down_w[j * D64 + d];
    }
    for (int i = t; i < GD * DINNER; i += 256) {
        int d = i & 31, j = i >> 5;
        s_ipxT[i] = in_proj_w[d * GD + j];
        s_ipzT[i] = in_proj_w[(d + DINNER) * GD + j];
    }
    for (int i = t; i < DINNER * 17; i += 256) {
        int d = i / 17, r = i % 17;
        s_xpT[i] = x_proj_w[r * DINNER + d];
    }
    for (int i = t; i < DINNER * GD; i += 256) {
        int j = i & 15, d = i >> 4;
        s_opT[i] = out_proj_w[j * DINNER + d];
    }
    for (int i = t; i < DSTATE * DINNER; i += 256) {
        int d = i & 31, s = i >> 5;
        s_AT[i] = -expf(A_log[d * DSTATE + s]);
    }
    if (t < DINNER) {
        s_cw4[t] = ((const float4*)conv_w)[t];
        s_cb[t] = conv_b[t]; s_dtw[t] = dt_proj_w[t];
        s_dtb[t] = dt_proj_b[t]; s_Dp[t] = D_param[t];
    }
    if (t < GD) { s_lng[t] = ln_g[t]; s_lnb[t] = ln_b[t]; s_lw[t] = to_logit_w[t]; }
    if (t == 0) s_lb = to_logit_b[0];
    __syncthreads();

    const float* rows = (const float*)s_rows4 + eb * 196;

    {
        float a0 = 0.f, a1 = 0.f, a2 = 0.f;
        #pragma unroll
        for (int d = 0; d < D64; ++d) {
            float w = s_downT[d * GD + lane16];
            a0 = fmaf(rows[d], w, a0);
            a1 = fmaf(rows[64 + d], w, a1);
            a2 = fmaf(rows[128 + d], w, a2);
        }
        s_g[eb * 49 + 0 * GD + lane16] = a0;
        s_g[eb * 49 + 1 * GD + lane16] = a1;
        s_g[eb * 49 + 2 * GD + lane16] = a2;
    }
    __syncthreads();

    const float* ge = s_g + eb * 49;

    float xsr[2][LSEQ];
    #pragma unroll
    for (int c = 0; c < 2; ++c) {
        int d = lane16 + 16 * c;
        float xl0 = 0.f, xl1 = 0.f, xl2 = 0.f;
        #pragma unroll
        for (int j = 0; j < GD; ++j) {
            float w = s_ipxT[j * DINNER + d];
            xl0 = fmaf(ge[j], w, xl0);
            xl1 = fmaf(ge[GD + j], w, xl1);
            xl2 = fmaf(ge[2 * GD + j], w, xl2);
        }
        float4 cw = s_cw4[d]; float cb = s_cb[d];
        float a0 = fmaf(xl0, cw.w, cb);
        float a1 = fmaf(xl1, cw.w, fmaf(xl0, cw.z, cb));
        float a2 = fmaf(xl2, cw.w, fmaf(xl1, cw.z, fmaf(xl0, cw.y, cb)));
        xsr[c][0] = a0 / (1.f + __expf(-a0));
        xsr[c][1] = a1 / (1.f + __expf(-a1));
        xsr[c][2] = a2 / (1.f + __expf(-a2));
        #pragma unroll
        for (int l = 0; l < LSEQ; ++l) s_xs[eb * 98 + l * DINNER + d] = xsr[c][l];
    }
    __syncthreads();

    {
        const float* xse = s_xs + eb * 98;
        int nr = (lane16 == 0) ? 2 : 1;
        for (int it = 0; it < nr; ++it) {
            int r = (it == 0) ? lane16 : 16;
            float a0 = 0.f, a1 = 0.f, a2 = 0.f;
            #pragma unroll
            for (int d = 0; d < DINNER; ++d) {
                float w = s_xpT[d * 17 + r];
                a0 = fmaf(xse[d], w, a0);
                a1 = fmaf(xse[DINNER + d], w, a1);
                a2 = fmaf(xse[2 * DINNER + d], w, a2);
            }
            s_dbc[eb * 49 + 0 * 17 + r] = a0;
            s_dbc[eb * 49 + 1 * 17 + r] = a1;
            s_dbc[eb * 49 + 2 * 17 + r] = a2;
        }
    }
    __syncthreads();

    {
        const float* dbce = s_dbc + eb * 49;
        float h[2][DSTATE];
        #pragma unroll
        for (int c = 0; c < 2; ++c)
            #pragma unroll
            for (int s = 0; s < DSTATE; ++s) h[c][s] = 0.f;
        #pragma unroll
        for (int l = 0; l < LSEQ; ++l) {
            float dtr = dbce[l * 17];
            float Bm[DSTATE], Cm[DSTATE];
            #pragma unroll
            for (int s = 0; s < DSTATE; ++s) {
                Bm[s] = dbce[l * 17 + 1 + s];
                Cm[s] = dbce[l * 17 + 9 + s];
            }
            #pragma unroll
            for (int c = 0; c < 2; ++c) {
                int d = lane16 + 16 * c;
                float pre = fmaf(dtr, s_dtw[d], s_dtb[d]);
                float dt  = (pre > 20.f) ? pre : __logf(1.f + __expf(pre));
                float xv  = xsr[c][l];
                float dtx = dt * xv;
                float acc = 0.f;
                #pragma unroll
                for (int s = 0; s < DSTATE; ++s) {
                    float dA = __expf(dt * s_AT[s * DINNER + d]);
                    h[c][s] = fmaf(dA, h[c][s], dtx * Bm[s]);
                    acc = fmaf(h[c][s], Cm[s], acc);
                }
                float y = fmaf(s_Dp[d], xv, acc);
                float zv = 0.f;
                #pragma unroll
                for (int j = 0; j < GD; ++j)
                    zv = fmaf(ge[l * GD + j], s_ipzT[j * DINNER + d], zv);
                float ys = y * (zv / (1.f + __expf(-zv)));
                s_xs[eb * 98 + l * DINNER + d] = ys;
            }
        }
    }
    __syncthreads();

    float lg[LSEQ];
    {
        const float* yse = s_xs + eb * 98;
        #pragma unroll
        for (int l = 0; l < LSEQ; ++l) {
            float a = 0.f;
            #pragma unroll
            for (int d = 0; d < DINNER; ++d)
                a = fmaf(yse[l * DINNER + d], s_opT[d * GD + lane16], a);
            float v = a + ge[l * GD + lane16];
            float sm = v, sq = v * v;
            #pragma unroll
            for (int m = 1; m <= 8; m <<= 1) {
                sm += __shfl_xor(sm, m, 64);
                sq += __shfl_xor(sq, m, 64);
            }
            float mu  = sm * (1.f / GD);
            float var = fmaxf(sq * (1.f / GD) - mu * mu, 0.f);
            float inv = rsqrtf(var + 1e-12f);
            float lo = fmaf(fmaf((v - mu) * inv, s_lng[lane16], s_lnb[lane16]),
                            s_lw[lane16], 0.f);
            #pragma unroll
            for (int m = 1; m <= 8; m <<= 1) lo += __shfl_xor(lo, m, 64);
            lg[l] = (lo + s_lb) * 1.25f;
        }
    }

    {
        float mx = fmaxf(lg[0], fmaxf(lg[1], lg[2]));
        float e0 = __expf(lg[0] - mx), e1 = __expf(lg[1] - mx), e2 = __expf(lg[2] - mx);
        float inv = 1.f / (e0 + e1 + e2);
        float w0 = e0 * inv, w1 = e1 * inv, w2 = e2 * inv;
        float4 r0 = s_rows4[eb * 49 + 0 * 16 + lane16];
        float4 r1 = s_rows4[eb * 49 + 1 * 16 + lane16];
        float4 r2 = s_rows4[eb * 49 + 2 * 16 + lane16];
        float4 r;
        r.x = w0 * r0.x + w1 * r1.x + w2 * r2.x;
        r.y = w0 * r0.y + w1 * r1.y + w2 * r2.y;
        r.z = w0 * r0.z + w1 * r1.z + w2 * r2.z;
        r.w = w0 * r0.w + w1 * r1.w + w2 * r2.w;
        ((float4*)out)[(size_t)b * 16 + lane16] = r;
    }
}

extern "C" void kernel_launch(void* const* d_in, const int* in_sizes, int n_in,
                              void* d_out, int out_size, void* d_ws, size_t ws_size,
                              hipStream_t stream) {
    const float* user      = (const float*)d_in[0];
    const float* item      = (const float*)d_in[1];
    const int*   erow      = (const int*)  d_in[2];
    const int*   ecol      = (const int*)  d_in[3];
    const float* eval_     = (const float*)d_in[4];
    const int*   nids      = (const int*)  d_in[5];
    const float* down_w    = (const float*)d_in[6];
    const float* in_proj_w = (const float*)d_in[7];
    const float* conv_w    = (const float*)d_in[8];
    const float* conv_b    = (const float*)d_in[9];
    const float* x_proj_w  = (const float*)d_in[10];
    const float* dt_proj_w = (const float*)d_in[11];
    const float* dt_proj_b = (const float*)d_in[12];
    const float* A_log     = (const float*)d_in[13];
    const float* D_param   = (const float*)d_in[14];
    const float* out_projw = (const float*)d_in[15];
    const float* ln_g      = (const float*)d_in[16];
    const float* ln_b      = (const float*)d_in[17];
    const float* to_lw     = (const float*)d_in[18];
    const float* to_lb     = (const float*)d_in[19];
    float* out = (float*)d_out;

    // workspace layout (~86 MB total)
    char* base = (char*)d_ws;
    float* embA = (float*)base;                                    // 64,000,000
    char* c = base + 64000000;
    // zeroed region (one memsetAsync): cnt | nidf | needf
    int* cnt   = (int*)c;                                          // 1,000,000
    unsigned char* nidf  = (unsigned char*)(c + 1000000);          //   250,000
    unsigned char* needf = (unsigned char*)(c + 1250000);          //   250,000
    size_t zbytes = 1500000;
    c += 1500032;                                                  // pad
    int* nrows    = (int*)c;  c += 64;
    int* cursor   = (int*)c;  c += (size_t)NTOT * 4;               // 1,000,000
    int* fpos     = (int*)c;  c += (size_t)NTOT * 4;               // 1,000,000
    int* offs     = (int*)c;  c += (size_t)(NTOT + 1) * 4 + 60;    // 1,000,064
    int* bsum     = (int*)c;  c += 1024;
    int* fbsum    = (int*)c;  c += 1024;
    int4* rowinfo = (int4*)c; c += (size_t)NTOT * 16;              // 4,000,000
    int2* colval  = (int2*)c;                                      // 10,000,000

    // ---- zero flags/counters in one stream-ordered memset ----
    hipMemsetAsync((void*)cnt, 0, zbytes, stream);

    // ---- flag marking (plain byte stores, no atomics) ----
    mark_nids_kernel<<<(BATCH + 255) / 256, 256, 0, stream>>>(nids, nidf, needf);
    mark_need_kernel<<<(NNZ / 4 + 255) / 256, 256, 0, stream>>>(erow, ecol, nidf, needf);

    // ---- build (sparse) CSR: hist -> 3-kernel dual scan -> cursor fill ----
    hist_kernel<<<(NNZ / 4 + 255) / 256, 256, 0, stream>>>(erow, needf, cnt);
    scan1_kernel<<<NBLK1, 256, 0, stream>>>(cnt, needf, offs, fpos, bsum, fbsum);
    scan2_kernel<<<1, 256, 0, stream>>>(bsum, fbsum);
    scan3_kernel<<<(NTOT + 255) / 256, 256, 0, stream>>>(offs, bsum, cnt, fpos, fbsum,
                                                         needf, cursor, rowinfo, nrows);
    fill_kernel<<<(NNZ / 4 + 255) / 256, 256, 0, stream>>>(erow, ecol, eval_, cursor,
                                                           needf, colval);

    // ---- layer 1 (compacted rows); layer 2 fused into final ----
    layer1_kernel<<<(NTOT + 15) / 16, 256, 0, stream>>>(user, item, nrows, rowinfo, colval, embA);

    // ---- fused head (incl. layer-2 gather): 16 elements per block ----
    final_kernel<<<BATCH / 16, 256, 0, stream>>>(nids, user, item, embA, offs, colval,
                                                 down_w, in_proj_w, conv_w, conv_b,
                                                 x_proj_w, dt_proj_w, dt_proj_b, A_log,
                                                 D_param, out_projw, ln_g, ln_b, to_lw, to_lb, out);
}